// Round 8
// baseline (302.582 us; speedup 1.0000x reference)
//
#include <hip/hip_runtime.h>
#include <hip/hip_bf16.h>
#include <cstdint>
#include <cstddef>

// Problem constants (R=45, L=384, D=512, E_REL=15, IN4=1024, HOPS=3)
#define LL      147456      // 384*384
#define NBLK    1152        // 24 dbase-groups x 48 h-groups (4 blocks/CU capacity)
#define CHB     8           // h values per block (2 per wave)
#define NPACK   288         // pack blocks (2 hd per thread)

typedef __attribute__((ext_vector_type(8))) short  short8;
typedef __attribute__((ext_vector_type(4))) float  f32x4;

// ---- workspace layout (bytes, 16B aligned) ----
#define EPACK_OFF   0u          // 6 planes * LL * 16B (bf16 E, plane-major, K=48)
#define MARG_OFF    14155776u   // LL*4
#define A_OFF       14745600u   // 384*512*4   A[h][c]
#define BTC_OFF     15532032u   // 512*384*4   Btc[c][d]  (c-major: f32x4 covers 16 d's)
#define UTGP_OFF    16318464u   // 6*512*16 (U plane-major [g][c] bf16x8)
#define XIN_OFF     16367616u   // 1024 f
#define KBUF_OFF    16371712u   // 512 f
#define VBUF_OFF    16373760u   // 512 f
#define PM_OFF      16377856u   // 1152 f
#define PL_OFF      16382464u   // 1152 f
#define PACC_OFF    16387072u   // 1152*512*4 = 2,359,296
#define BLKF_OFF    18746368u   // NPACK ints

#define SKIP_LD     20.0f       // dropped mass bound ~3e-4 relative: below tolerance

static __device__ __forceinline__ ushort f2bf(float x) {
  uint u = __float_as_uint(x);
  return (ushort)((u + 0x7fffu + ((u >> 16) & 1u)) >> 16);   // RNE
}
static __device__ __forceinline__ float lrelu(float x) { return fmaxf(x, 0.01f * x); }

// ------------------------------------------------------------------
// Merged prep (unchanged known-good). GEMM blocks FIRST so pack backfills.
__global__ __launch_bounds__(256) void k_prep(
    const float* __restrict__ E, uint4* __restrict__ ep,
    float* __restrict__ marg, int* __restrict__ blkflags,
    const float* __restrict__ H, const float* __restrict__ Wc,
    const float* __restrict__ rel, const float* __restrict__ bc,
    float* __restrict__ A, float* __restrict__ Btc, uint4* __restrict__ Utgp) {
  __shared__ float Hs[4][512];
  __shared__ float Ps[4][512];
  __shared__ int fsh;
  int b = blockIdx.x, t = threadIdx.x;
  if (b < 192) {
    bool roleA = (b < 96);
    int g0 = (roleA ? b : b - 96) * 4;
    const float* Wcp = Wc + (size_t)(roleA ? 0 : 527) * 512;
    for (int i = t; i < 4 * 512; i += 256) Hs[i >> 9][i & 511] = H[(size_t)g0 * 512 + i];
    __syncthreads();
    int cq = t & 127, q = t >> 7;
    int c0 = cq * 4;
    f32x4 acc[4];
#pragma unroll
    for (int i = 0; i < 4; ++i) acc[i] = (f32x4){0.f, 0.f, 0.f, 0.f};
    for (int k = q * 256; k < q * 256 + 256; ++k) {
      f32x4 wv = *(const f32x4*)&Wcp[(size_t)k * 512 + c0];
#pragma unroll
      for (int i = 0; i < 4; ++i) { float hv = Hs[i][k]; acc[i] += hv * wv; }
    }
    if (q == 1) {
#pragma unroll
      for (int i = 0; i < 4; ++i) *(f32x4*)&Ps[i][c0] = acc[i];
    }
    __syncthreads();
    if (q == 0) {
#pragma unroll
      for (int i = 0; i < 4; ++i) {
        acc[i] += *(const f32x4*)&Ps[i][c0];
        if (roleA) {
          *(f32x4*)&A[(size_t)(g0 + i) * 512 + c0] = acc[i];
        } else {
#pragma unroll
          for (int j = 0; j < 4; ++j) Btc[(size_t)(c0 + j) * 384 + (g0 + i)] = acc[i][j];
        }
      }
    }
  } else if (b == 192) {
    for (int c = t; c < 512; c += 256) {
      float uv[48];
#pragma unroll
      for (int k = 0; k < 45; ++k) {
        float s = 0.f;
#pragma unroll
        for (int e = 0; e < 15; ++e) s += rel[k * 15 + e] * Wc[(size_t)(512 + e) * 512 + c];
        uv[k] = s;
      }
      uv[45] = bc[c]; uv[46] = 0.f; uv[47] = 0.f;
#pragma unroll
      for (int g = 0; g < 6; ++g) {
        uint w[4];
#pragma unroll
        for (int p = 0; p < 4; ++p)
          w[p] = (uint)f2bf(uv[g * 8 + 2 * p]) | ((uint)f2bf(uv[g * 8 + 2 * p + 1]) << 16);
        uint4 v; v.x = w[0]; v.y = w[1]; v.z = w[2]; v.w = w[3];
        Utgp[g * 512 + c] = v;
      }
    }
  } else {
    // pack role: 2 hd per thread, all 45 plane loads (float2) in flight
    if (t == 0) fsh = 0;
    int bp = b - 193;
    size_t hd0 = (size_t)bp * 512 + 2 * t;
    float2 ev[46];
#pragma unroll
    for (int r = 0; r < 45; ++r) ev[r] = *(const float2*)&E[(size_t)r * LL + hd0];
    ev[45] = make_float2(1.0f, 1.0f);   // slot45 = 1.0 for bc-fold
    float s0 = 0.f, s1 = 0.f;
#pragma unroll
    for (int r = 0; r < 45; ++r) { s0 += ev[r].x; s1 += ev[r].y; }
#pragma unroll
    for (int o = 0; o < 6; ++o) {
      uint wa[4], wb[4];
#pragma unroll
      for (int p = 0; p < 4; ++p) {
        int r0 = 8 * o + 2 * p, r1 = r0 + 1;
        float a0 = (r0 < 46) ? ev[r0].x : 0.f, a1 = (r1 < 46) ? ev[r1].x : 0.f;
        float b0 = (r0 < 46) ? ev[r0].y : 0.f, b1 = (r1 < 46) ? ev[r1].y : 0.f;
        wa[p] = (uint)f2bf(a0) | ((uint)f2bf(a1) << 16);
        wb[p] = (uint)f2bf(b0) | ((uint)f2bf(b1) << 16);
      }
      uint4 va; va.x = wa[0]; va.y = wa[1]; va.z = wa[2]; va.w = wa[3];
      uint4 vb; vb.x = wb[0]; vb.y = wb[1]; vb.z = wb[2]; vb.w = wb[3];
      ep[(size_t)o * LL + hd0] = va;
      ep[(size_t)o * LL + hd0 + 1] = vb;
    }
    *(float2*)&marg[hd0] = make_float2(s0, s1);
    int f = (s0 > 1e-6f ? 1 : 0) | (s0 > 1e-7f ? 2 : 0) | (s0 > 1e-8f ? 4 : 0)
          | (s1 > 1e-6f ? 1 : 0) | (s1 > 1e-7f ? 2 : 0) | (s1 > 1e-8f ? 4 : 0);
#pragma unroll
    for (int d = 1; d < 64; d <<= 1) f |= __shfl_xor(f, d);
    __syncthreads();
    if ((t & 63) == 0) atomicOr(&fsh, f);
    __syncthreads();
    if (t == 0) blkflags[bp] = fsh;
  }
}

// -------------------- leading GEMV (kv split), 64 blocks x 16 cols --------------------
__global__ __launch_bounds__(256) void k_gemv(const float* __restrict__ W, const float* __restrict__ bias,
                                              const float* __restrict__ xA, const float* __restrict__ xB,
                                              float* __restrict__ kbuf, float* __restrict__ vbuf) {
  __shared__ float xs[1024];
  __shared__ float red[256];
  int t = threadIdx.x;
  for (int i = t; i < 1024; i += 256) xs[i] = (i < 512) ? xA[i] : xB[i - 512];
  __syncthreads();
  int jj = t & 15, kq = t >> 4;           // 16 k-slices of 64
  int j = blockIdx.x * 16 + jj;
  float acc = 0.f;
#pragma unroll 8
  for (int k = kq * 64; k < kq * 64 + 64; ++k) acc = fmaf(xs[k], W[(size_t)k * 1024 + j], acc);
  red[kq * 16 + jj] = acc;
  __syncthreads();
  if (kq == 0) {
    float s = bias[j];
#pragma unroll
    for (int q = 0; q < 16; ++q) s += red[q * 16 + jj];
    if (j < 512) kbuf[j] = tanhf(s);
    else vbuf[j - 512] = lrelu(s);
  }
}

// -------------------- fused scores + block-softmax + PV --------------------
// CHB=8, grid 1152, LDS 34.3KB -> 4 blocks/CU capacity (16 waves/CU in the
// main round). b0 granules 0-3 staged in LDS (dominant path, all lanes);
// b1 granules 4-5 read from global (L2-hot, qq<2 half-wave only, pipelined).
__global__ __launch_bounds__(256, 4) void k_fused(
    const uint4* __restrict__ ep, const float* __restrict__ marg,
    const float* __restrict__ A, const float* __restrict__ Btc,
    const uint4* __restrict__ Utgp, const int* __restrict__ blkflags,
    const float* __restrict__ kvec,
    float* __restrict__ pm, float* __restrict__ pl, float* __restrict__ pacc) {
  __shared__ __align__(16) uint4 uthF[4 * 512];   // 32KB: granules 0-3 only
  __shared__ float sbuf[CHB * 16];
  __shared__ float redw[8];
  __shared__ float paccs[256];
  __shared__ int fsh;
  int t = threadIdx.x, b = blockIdx.x;
  int dbt = b / 48, hg = b - dbt * 48;
  int dbase = dbt * 16, h0 = hg * CHB;
  int lane = t & 63, wid = t >> 6;
  int l15 = lane & 15, qq = lane >> 4;

  if (t == 0) fsh = 0;
  for (int i = t; i < 4 * 512; i += 256) uthF[i] = Utgp[i];
  int f = 0;
  for (int i = t; i < NPACK; i += 256) f |= blkflags[i];
#pragma unroll
  for (int d = 1; d < 64; d <<= 1) f |= __shfl_xor(f, d);

  const short8 zero8 = (short8){0, 0, 0, 0, 0, 0, 0, 0};
  short8 a0[2], a1[2];
  f32x4 wq[2];
#pragma unroll
  for (int k3 = 0; k3 < 2; ++k3) {
    int h = h0 + wid * 2 + k3;
    int hda = h * 384 + dbase + l15;
    uint4 r0 = ep[(size_t)qq * LL + hda];
    a0[k3] = *(short8*)&r0;
    if (qq < 2) { uint4 r1 = ep[(size_t)(4 + qq) * LL + hda]; a1[k3] = *(short8*)&r1; }
    else a1[k3] = zero8;
    wq[k3] = *(const f32x4*)&marg[h * 384 + dbase + qq * 4];
  }
  __syncthreads();
  if ((t & 63) == 0) atomicOr(&fsh, f);

  // ---------------- phase A: scores ----------------
  float sp[2][4];
#pragma unroll
  for (int k3 = 0; k3 < 2; ++k3)
#pragma unroll
    for (int j = 0; j < 4; ++j) sp[k3][j] = 0.f;

  for (int half = 0; half < 2; ++half) {
    float kreg[16];
#pragma unroll
    for (int tt = 0; tt < 16; ++tt) kreg[tt] = kvec[half * 256 + tt * 16 + l15];
#pragma unroll 4
    for (int tt = 0; tt < 16; ++tt) {
      int c = half * 256 + tt * 16 + l15;
      short8 b0 = *(short8*)&uthF[qq * 512 + c];
      short8 b1 = (qq < 2) ? *(const short8*)&Utgp[(4 + qq) * 512 + c] : zero8;
      f32x4 btv = *(const f32x4*)&Btc[(size_t)c * 384 + dbase + qq * 4];
      const float* Ap = &A[(size_t)(h0 + wid * 2) * 512 + c];
      float av[2]; av[0] = Ap[0]; av[1] = Ap[512];
#pragma unroll
      for (int k3 = 0; k3 < 2; ++k3) {
        f32x4 cc = (f32x4){0.f, 0.f, 0.f, 0.f};
        cc = __builtin_amdgcn_mfma_f32_16x16x32_bf16(a0[k3], b0, cc, 0, 0, 0);
        cc = __builtin_amdgcn_mfma_f32_16x16x32_bf16(a1[k3], b1, cc, 0, 0, 0);
        float aw = av[k3];
        float x0 = cc[0] + wq[k3][0] * (aw + btv[0]); float mb0 = fmaxf(x0, 0.01f * x0);
        float x1 = cc[1] + wq[k3][1] * (aw + btv[1]); float mb1 = fmaxf(x1, 0.01f * x1);
        float x2 = cc[2] + wq[k3][2] * (aw + btv[2]); float mb2 = fmaxf(x2, 0.01f * x2);
        float x3 = cc[3] + wq[k3][3] * (aw + btv[3]); float mb3 = fmaxf(x3, 0.01f * x3);
        sp[k3][0] = fmaf(mb0, kreg[tt], sp[k3][0]);
        sp[k3][1] = fmaf(mb1, kreg[tt], sp[k3][1]);
        sp[k3][2] = fmaf(mb2, kreg[tt], sp[k3][2]);
        sp[k3][3] = fmaf(mb3, kreg[tt], sp[k3][3]);
      }
    }
  }
#pragma unroll
  for (int k3 = 0; k3 < 2; ++k3)
#pragma unroll
    for (int j = 0; j < 4; ++j) {
#pragma unroll
      for (int d = 1; d < 16; d <<= 1) sp[k3][j] += __shfl_xor(sp[k3][j], d);
    }
  __syncthreads();   // atomicOr(fsh) complete
  float thr = (fsh & 1) ? 1e-6f : ((fsh & 2) ? 1e-7f : 1e-8f);
  if (l15 == 0) {
#pragma unroll
    for (int k3 = 0; k3 < 2; ++k3) {
      int base = (wid * 2 + k3) * 16 + qq * 4;
#pragma unroll
      for (int j = 0; j < 4; ++j)
        sbuf[base + j] = (wq[k3][j] > thr) ? sp[k3][j] : -1e30f;
    }
  }
  __syncthreads();

  // ---------------- block softmax ----------------
  float sv = (t < CHB * 16) ? sbuf[t] : -1e30f;
  float m = sv;
#pragma unroll
  for (int d = 1; d < 64; d <<= 1) m = fmaxf(m, __shfl_xor(m, d));
  if (lane == 0) redw[wid] = m;
  __syncthreads();
  float mloc = fmaxf(fmaxf(redw[0], redw[1]), fmaxf(redw[2], redw[3]));
  float e = (t < CHB * 16) ? __expf(sv - mloc) : 0.f;
#pragma unroll
  for (int d = 1; d < 64; d <<= 1) e += __shfl_xor(e, d);
  if (lane == 0) redw[4 + wid] = e;
  __syncthreads();
  if (t == 0) { pm[b] = mloc; pl[b] = redw[4] + redw[5] + redw[6] + redw[7]; }

  // ---------------- phase B: PV (reuses a-frags/wq/uthF) ----------------
  float pvw[2][4];
#pragma unroll
  for (int k3 = 0; k3 < 2; ++k3)
#pragma unroll
    for (int j = 0; j < 4; ++j)
      pvw[k3][j] = __expf(sbuf[(wid * 2 + k3) * 16 + qq * 4 + j] - mloc);

  for (int half = 0; half < 2; ++half) {
    paccs[t] = 0.f;
    __syncthreads();
#pragma unroll 4
    for (int tt = 0; tt < 16; ++tt) {
      int c = half * 256 + tt * 16 + l15;
      short8 b0 = *(short8*)&uthF[qq * 512 + c];
      short8 b1 = (qq < 2) ? *(const short8*)&Utgp[(4 + qq) * 512 + c] : zero8;
      f32x4 btv = *(const f32x4*)&Btc[(size_t)c * 384 + dbase + qq * 4];
      const float* Ap = &A[(size_t)(h0 + wid * 2) * 512 + c];
      float av[2]; av[0] = Ap[0]; av[1] = Ap[512];
      float acc_t = 0.f;
#pragma unroll
      for (int k3 = 0; k3 < 2; ++k3) {
        f32x4 cc = (f32x4){0.f, 0.f, 0.f, 0.f};
        cc = __builtin_amdgcn_mfma_f32_16x16x32_bf16(a0[k3], b0, cc, 0, 0, 0);
        cc = __builtin_amdgcn_mfma_f32_16x16x32_bf16(a1[k3], b1, cc, 0, 0, 0);
        float aw = av[k3];
        float x0 = cc[0] + wq[k3][0] * (aw + btv[0]); float mb0 = fmaxf(x0, 0.01f * x0);
        float x1 = cc[1] + wq[k3][1] * (aw + btv[1]); float mb1 = fmaxf(x1, 0.01f * x1);
        float x2 = cc[2] + wq[k3][2] * (aw + btv[2]); float mb2 = fmaxf(x2, 0.01f * x2);
        float x3 = cc[3] + wq[k3][3] * (aw + btv[3]); float mb3 = fmaxf(x3, 0.01f * x3);
        acc_t = fmaf(pvw[k3][0], mb0, fmaf(pvw[k3][1], mb1,
                fmaf(pvw[k3][2], mb2, fmaf(pvw[k3][3], mb3, acc_t))));
      }
      acc_t += __shfl_xor(acc_t, 16);
      acc_t += __shfl_xor(acc_t, 32);
      if (lane < 16) atomicAdd(&paccs[tt * 16 + l15], acc_t);
    }
    __syncthreads();
    pacc[(size_t)b * 512 + half * 256 + t] = paccs[t];
    __syncthreads();
  }
}

// -------------------- combine + trailing GEMV fused (64 blocks x 16 cols) --------------------
__global__ __launch_bounds__(256) void k_gemvc(
    const float* __restrict__ W, const float* __restrict__ bias,
    const float* __restrict__ vbuf, const float* __restrict__ pm,
    const float* __restrict__ pl, const float* __restrict__ pacc,
    float* __restrict__ outA, float* __restrict__ out2) {
  __shared__ float xs[1024];
  __shared__ float sc[NBLK];
  __shared__ int slist[NBLK];
  __shared__ int scnt_sh;
  __shared__ float redm[8];
  __shared__ float red[256];
  int t = threadIdx.x;
  int lane = t & 63, wid = t >> 6;

  float m = -1e30f;
  for (int i = t; i < NBLK; i += 256) m = fmaxf(m, pm[i]);
#pragma unroll
  for (int d = 1; d < 64; d <<= 1) m = fmaxf(m, __shfl_xor(m, d));
  if (lane == 0) redm[wid] = m;
  __syncthreads();
  float M = fmaxf(fmaxf(redm[0], redm[1]), fmaxf(redm[2], redm[3]));
  float ls = 0.f;
  for (int i = t; i < NBLK; i += 256) {
    float d = pm[i] - M;
    float e = (d < -SKIP_LD) ? 0.f : __expf(d);
    sc[i] = e;
    ls += e * pl[i];
  }
#pragma unroll
  for (int d = 1; d < 64; d <<= 1) ls += __shfl_xor(ls, d);
  if (lane == 0) redm[4 + wid] = ls;
  __syncthreads();
  float L = redm[4] + redm[5] + redm[6] + redm[7];

  if (wid == 0) {   // deterministic survivor compaction
    int cnt = 0;
#pragma unroll
    for (int rnd = 0; rnd < NBLK / 64; ++rnd) {
      int bb = rnd * 64 + lane;
      bool p = sc[bb] > 0.f;
      unsigned long long mask = __ballot(p);
      int off = __popcll(mask & ((1ull << lane) - 1ull));
      if (p) slist[cnt + off] = bb;
      cnt += __popcll(mask);
    }
    if (lane == 0) scnt_sh = cnt;
  }
  __syncthreads();
  int S = scnt_sh;
  for (int c = t; c < 512; c += 256) xs[c] = vbuf[c];
#pragma unroll
  for (int half = 0; half < 2; ++half) {
    int c = t + half * 256;
    float s = 0.f;
    for (int k = 0; k < S; ++k) {
      int bb = slist[k];
      s += pacc[(size_t)bb * 512 + c] * sc[bb];
    }
    xs[512 + c] = s / L;
  }
  __syncthreads();

  int jj = t & 15, kq = t >> 4;           // 16 k-slices of 64
  int j = blockIdx.x * 16 + jj;
  float acc = 0.f;
#pragma unroll 8
  for (int k = kq * 64; k < kq * 64 + 64; ++k) acc = fmaf(xs[k], W[(size_t)k * 1024 + j], acc);
  red[kq * 16 + jj] = acc;
  __syncthreads();
  if (kq == 0) {
    float s = bias[j];
#pragma unroll
    for (int q = 0; q < 16; ++q) s += red[q * 16 + jj];
    float rv = lrelu(s);
    outA[j] = rv;
    if (out2) out2[j] = rv;
  }
}

// ------------------------------------------------------------------
extern "C" void kernel_launch(void* const* d_in, const int* in_sizes, int n_in,
                              void* d_out, int out_size, void* d_ws, size_t ws_size,
                              hipStream_t stream) {
  const float* E   = (const float*)d_in[0];
  const float* H   = (const float*)d_in[1];
  const float* e1  = (const float*)d_in[2];
  const float* e2  = (const float*)d_in[3];
  const float* rel = (const float*)d_in[5];
  const float* Wc  = (const float*)d_in[6];
  const float* bc  = (const float*)d_in[7];
  const float* Wk  = (const float*)d_in[8];
  const float* bk  = (const float*)d_in[9];
  const float* Wh  = (const float*)d_in[10];
  const float* bh  = (const float*)d_in[11];

  char* ws = (char*)d_ws;
  uint4*  ep     = (uint4*)(ws + EPACK_OFF);
  float*  marg   = (float*)(ws + MARG_OFF);
  float*  Abuf   = (float*)(ws + A_OFF);
  float*  Btc    = (float*)(ws + BTC_OFF);
  uint4*  Utgp   = (uint4*)(ws + UTGP_OFF);
  float*  xin    = (float*)(ws + XIN_OFF);
  float*  kbuf   = (float*)(ws + KBUF_OFF);
  float*  vbuf   = (float*)(ws + VBUF_OFF);
  float*  pm     = (float*)(ws + PM_OFF);
  float*  pl     = (float*)(ws + PL_OFF);
  float*  pacc   = (float*)(ws + PACC_OFF);
  int*    blkf   = (int*)(ws + BLKF_OFF);

  k_prep<<<481, 256, 0, stream>>>(E, ep, marg, blkf, H, Wc, rel, bc, Abuf, Btc, Utgp);

  for (int hop = 0; hop < 3; ++hop) {
    const float* Wki = Wk + (size_t)hop * 1024 * 1024;
    const float* bki = bk + (size_t)hop * 1024;
    const float* Whi = Wh + (size_t)hop * 1024 * 1024;
    const float* bhi = bh + (size_t)hop * 1024;
    k_gemv<<<64, 256, 0, stream>>>(Wki, bki, hop == 0 ? e1 : xin,
                                   hop == 0 ? e2 : xin + 512, kbuf, vbuf);
    k_fused<<<NBLK, 256, 0, stream>>>(ep, marg, Abuf, Btc, Utgp, blkf, kbuf,
                                      pm, pl, pacc);
    k_gemvc<<<64, 256, 0, stream>>>(Whi, bhi, vbuf, pm, pl, pacc, xin,
                                    hop == 2 ? (float*)d_out : (float*)nullptr);
  }
}

// Round 9
// 268.464 us; speedup vs baseline: 1.1271x; 1.1271x over previous
//
#include <hip/hip_runtime.h>
#include <hip/hip_bf16.h>
#include <cstdint>
#include <cstddef>

// Problem constants (R=45, L=384, D=512, E_REL=15, IN4=1024, HOPS=3)
#define LL      147456      // 384*384
#define NBLK    1152        // 24 dbase-groups x 48 h-groups (4 blocks/CU capacity)
#define CHB     8           // h values per block (2 per wave)
#define NPACK   288         // pack blocks (2 hd per thread)

typedef __attribute__((ext_vector_type(8))) short  short8;
typedef __attribute__((ext_vector_type(4))) float  f32x4;

// ---- workspace layout (bytes, 16B aligned) ----
#define EPACK_OFF   0u          // 6 planes * LL * 16B (bf16 E, plane-major, K=48)
#define MARG_OFF    14155776u   // LL*4
#define A_OFF       14745600u   // 384*512*4   A[h][c]
#define BTC_OFF     15532032u   // 512*384*4   Btc[c][d]  (c-major: f32x4 covers 16 d's)
#define UTGP_OFF    16318464u   // 6*512*16 (U plane-major [g][c] bf16x8)
#define XIN_OFF     16367616u   // 1024 f
#define KBUF_OFF    16371712u   // 512 f
#define VBUF_OFF    16373760u   // 512 f
#define PM_OFF      16377856u   // 1152 f
#define PL_OFF      16382464u   // 1152 f
#define PACC_OFF    16387072u   // 1152*512*4 = 2,359,296
#define BLKF_OFF    18746368u   // NPACK ints

#define SKIP_LD     20.0f       // dropped mass bound ~3e-4 relative: below tolerance

static __device__ __forceinline__ ushort f2bf(float x) {
  uint u = __float_as_uint(x);
  return (ushort)((u + 0x7fffu + ((u >> 16) & 1u)) >> 16);   // RNE
}
static __device__ __forceinline__ float lrelu(float x) { return fmaxf(x, 0.01f * x); }

// ------------------------------------------------------------------
// Merged prep (unchanged known-good). GEMM blocks FIRST so pack backfills.
__global__ __launch_bounds__(256) void k_prep(
    const float* __restrict__ E, uint4* __restrict__ ep,
    float* __restrict__ marg, int* __restrict__ blkflags,
    const float* __restrict__ H, const float* __restrict__ Wc,
    const float* __restrict__ rel, const float* __restrict__ bc,
    float* __restrict__ A, float* __restrict__ Btc, uint4* __restrict__ Utgp) {
  __shared__ float Hs[4][512];
  __shared__ float Ps[4][512];
  __shared__ int fsh;
  int b = blockIdx.x, t = threadIdx.x;
  if (b < 192) {
    bool roleA = (b < 96);
    int g0 = (roleA ? b : b - 96) * 4;
    const float* Wcp = Wc + (size_t)(roleA ? 0 : 527) * 512;
    for (int i = t; i < 4 * 512; i += 256) Hs[i >> 9][i & 511] = H[(size_t)g0 * 512 + i];
    __syncthreads();
    int cq = t & 127, q = t >> 7;
    int c0 = cq * 4;
    f32x4 acc[4];
#pragma unroll
    for (int i = 0; i < 4; ++i) acc[i] = (f32x4){0.f, 0.f, 0.f, 0.f};
    for (int k = q * 256; k < q * 256 + 256; ++k) {
      f32x4 wv = *(const f32x4*)&Wcp[(size_t)k * 512 + c0];
#pragma unroll
      for (int i = 0; i < 4; ++i) { float hv = Hs[i][k]; acc[i] += hv * wv; }
    }
    if (q == 1) {
#pragma unroll
      for (int i = 0; i < 4; ++i) *(f32x4*)&Ps[i][c0] = acc[i];
    }
    __syncthreads();
    if (q == 0) {
#pragma unroll
      for (int i = 0; i < 4; ++i) {
        acc[i] += *(const f32x4*)&Ps[i][c0];
        if (roleA) {
          *(f32x4*)&A[(size_t)(g0 + i) * 512 + c0] = acc[i];
        } else {
#pragma unroll
          for (int j = 0; j < 4; ++j) Btc[(size_t)(c0 + j) * 384 + (g0 + i)] = acc[i][j];
        }
      }
    }
  } else if (b == 192) {
    for (int c = t; c < 512; c += 256) {
      float uv[48];
#pragma unroll
      for (int k = 0; k < 45; ++k) {
        float s = 0.f;
#pragma unroll
        for (int e = 0; e < 15; ++e) s += rel[k * 15 + e] * Wc[(size_t)(512 + e) * 512 + c];
        uv[k] = s;
      }
      uv[45] = bc[c]; uv[46] = 0.f; uv[47] = 0.f;
#pragma unroll
      for (int g = 0; g < 6; ++g) {
        uint w[4];
#pragma unroll
        for (int p = 0; p < 4; ++p)
          w[p] = (uint)f2bf(uv[g * 8 + 2 * p]) | ((uint)f2bf(uv[g * 8 + 2 * p + 1]) << 16);
        uint4 v; v.x = w[0]; v.y = w[1]; v.z = w[2]; v.w = w[3];
        Utgp[g * 512 + c] = v;
      }
    }
  } else {
    // pack role: 2 hd per thread, all 45 plane loads (float2) in flight
    if (t == 0) fsh = 0;
    int bp = b - 193;
    size_t hd0 = (size_t)bp * 512 + 2 * t;
    float2 ev[46];
#pragma unroll
    for (int r = 0; r < 45; ++r) ev[r] = *(const float2*)&E[(size_t)r * LL + hd0];
    ev[45] = make_float2(1.0f, 1.0f);   // slot45 = 1.0 for bc-fold
    float s0 = 0.f, s1 = 0.f;
#pragma unroll
    for (int r = 0; r < 45; ++r) { s0 += ev[r].x; s1 += ev[r].y; }
#pragma unroll
    for (int o = 0; o < 6; ++o) {
      uint wa[4], wb[4];
#pragma unroll
      for (int p = 0; p < 4; ++p) {
        int r0 = 8 * o + 2 * p, r1 = r0 + 1;
        float a0 = (r0 < 46) ? ev[r0].x : 0.f, a1 = (r1 < 46) ? ev[r1].x : 0.f;
        float b0 = (r0 < 46) ? ev[r0].y : 0.f, b1 = (r1 < 46) ? ev[r1].y : 0.f;
        wa[p] = (uint)f2bf(a0) | ((uint)f2bf(a1) << 16);
        wb[p] = (uint)f2bf(b0) | ((uint)f2bf(b1) << 16);
      }
      uint4 va; va.x = wa[0]; va.y = wa[1]; va.z = wa[2]; va.w = wa[3];
      uint4 vb; vb.x = wb[0]; vb.y = wb[1]; vb.z = wb[2]; vb.w = wb[3];
      ep[(size_t)o * LL + hd0] = va;
      ep[(size_t)o * LL + hd0 + 1] = vb;
    }
    *(float2*)&marg[hd0] = make_float2(s0, s1);
    int f = (s0 > 1e-6f ? 1 : 0) | (s0 > 1e-7f ? 2 : 0) | (s0 > 1e-8f ? 4 : 0)
          | (s1 > 1e-6f ? 1 : 0) | (s1 > 1e-7f ? 2 : 0) | (s1 > 1e-8f ? 4 : 0);
#pragma unroll
    for (int d = 1; d < 64; d <<= 1) f |= __shfl_xor(f, d);
    __syncthreads();
    if ((t & 63) == 0) atomicOr(&fsh, f);
    __syncthreads();
    if (t == 0) blkflags[bp] = fsh;
  }
}

// -------------------- leading GEMV (kv split), 64 blocks x 16 cols --------------------
__global__ __launch_bounds__(256) void k_gemv(const float* __restrict__ W, const float* __restrict__ bias,
                                              const float* __restrict__ xA, const float* __restrict__ xB,
                                              float* __restrict__ kbuf, float* __restrict__ vbuf) {
  __shared__ float xs[1024];
  __shared__ float red[256];
  int t = threadIdx.x;
  for (int i = t; i < 1024; i += 256) xs[i] = (i < 512) ? xA[i] : xB[i - 512];
  __syncthreads();
  int jj = t & 15, kq = t >> 4;           // 16 k-slices of 64
  int j = blockIdx.x * 16 + jj;
  float acc = 0.f;
#pragma unroll 8
  for (int k = kq * 64; k < kq * 64 + 64; ++k) acc = fmaf(xs[k], W[(size_t)k * 1024 + j], acc);
  red[kq * 16 + jj] = acc;
  __syncthreads();
  if (kq == 0) {
    float s = bias[j];
#pragma unroll
    for (int q = 0; q < 16; ++q) s += red[q * 16 + jj];
    if (j < 512) kbuf[j] = tanhf(s);
    else vbuf[j - 512] = lrelu(s);
  }
}

// -------------------- fused scores + block-softmax + PV --------------------
// SINGLE-VARIABLE change vs R8: __launch_bounds__(256,3) (was (256,4)).
// (256,4) forced VGPR=64 -> ~22MB scratch spill (WRITE_SIZE smoking gun).
// (256,3) allows ~170 VGPR; expected ~72-96 -> no spill; LDS 34KB still
// admits 4 blocks/CU if VGPR <= 128.
__global__ __launch_bounds__(256, 3) void k_fused(
    const uint4* __restrict__ ep, const float* __restrict__ marg,
    const float* __restrict__ A, const float* __restrict__ Btc,
    const uint4* __restrict__ Utgp, const int* __restrict__ blkflags,
    const float* __restrict__ kvec,
    float* __restrict__ pm, float* __restrict__ pl, float* __restrict__ pacc) {
  __shared__ __align__(16) uint4 uthF[4 * 512];   // 32KB: granules 0-3 only
  __shared__ float sbuf[CHB * 16];
  __shared__ float redw[8];
  __shared__ float paccs[256];
  __shared__ int fsh;
  int t = threadIdx.x, b = blockIdx.x;
  int dbt = b / 48, hg = b - dbt * 48;
  int dbase = dbt * 16, h0 = hg * CHB;
  int lane = t & 63, wid = t >> 6;
  int l15 = lane & 15, qq = lane >> 4;

  if (t == 0) fsh = 0;
  for (int i = t; i < 4 * 512; i += 256) uthF[i] = Utgp[i];
  int f = 0;
  for (int i = t; i < NPACK; i += 256) f |= blkflags[i];
#pragma unroll
  for (int d = 1; d < 64; d <<= 1) f |= __shfl_xor(f, d);

  const short8 zero8 = (short8){0, 0, 0, 0, 0, 0, 0, 0};
  short8 a0[2], a1[2];
  f32x4 wq[2];
#pragma unroll
  for (int k3 = 0; k3 < 2; ++k3) {
    int h = h0 + wid * 2 + k3;
    int hda = h * 384 + dbase + l15;
    uint4 r0 = ep[(size_t)qq * LL + hda];
    a0[k3] = *(short8*)&r0;
    if (qq < 2) { uint4 r1 = ep[(size_t)(4 + qq) * LL + hda]; a1[k3] = *(short8*)&r1; }
    else a1[k3] = zero8;
    wq[k3] = *(const f32x4*)&marg[h * 384 + dbase + qq * 4];
  }
  __syncthreads();
  if ((t & 63) == 0) atomicOr(&fsh, f);

  // ---------------- phase A: scores ----------------
  float sp[2][4];
#pragma unroll
  for (int k3 = 0; k3 < 2; ++k3)
#pragma unroll
    for (int j = 0; j < 4; ++j) sp[k3][j] = 0.f;

  for (int half = 0; half < 2; ++half) {
    float kreg[16];
#pragma unroll
    for (int tt = 0; tt < 16; ++tt) kreg[tt] = kvec[half * 256 + tt * 16 + l15];
#pragma unroll 4
    for (int tt = 0; tt < 16; ++tt) {
      int c = half * 256 + tt * 16 + l15;
      short8 b0 = *(short8*)&uthF[qq * 512 + c];
      short8 b1 = (qq < 2) ? *(const short8*)&Utgp[(4 + qq) * 512 + c] : zero8;
      f32x4 btv = *(const f32x4*)&Btc[(size_t)c * 384 + dbase + qq * 4];
      const float* Ap = &A[(size_t)(h0 + wid * 2) * 512 + c];
      float av[2]; av[0] = Ap[0]; av[1] = Ap[512];
#pragma unroll
      for (int k3 = 0; k3 < 2; ++k3) {
        f32x4 cc = (f32x4){0.f, 0.f, 0.f, 0.f};
        cc = __builtin_amdgcn_mfma_f32_16x16x32_bf16(a0[k3], b0, cc, 0, 0, 0);
        cc = __builtin_amdgcn_mfma_f32_16x16x32_bf16(a1[k3], b1, cc, 0, 0, 0);
        float aw = av[k3];
        float x0 = cc[0] + wq[k3][0] * (aw + btv[0]); float mb0 = fmaxf(x0, 0.01f * x0);
        float x1 = cc[1] + wq[k3][1] * (aw + btv[1]); float mb1 = fmaxf(x1, 0.01f * x1);
        float x2 = cc[2] + wq[k3][2] * (aw + btv[2]); float mb2 = fmaxf(x2, 0.01f * x2);
        float x3 = cc[3] + wq[k3][3] * (aw + btv[3]); float mb3 = fmaxf(x3, 0.01f * x3);
        sp[k3][0] = fmaf(mb0, kreg[tt], sp[k3][0]);
        sp[k3][1] = fmaf(mb1, kreg[tt], sp[k3][1]);
        sp[k3][2] = fmaf(mb2, kreg[tt], sp[k3][2]);
        sp[k3][3] = fmaf(mb3, kreg[tt], sp[k3][3]);
      }
    }
  }
#pragma unroll
  for (int k3 = 0; k3 < 2; ++k3)
#pragma unroll
    for (int j = 0; j < 4; ++j) {
#pragma unroll
      for (int d = 1; d < 16; d <<= 1) sp[k3][j] += __shfl_xor(sp[k3][j], d);
    }
  __syncthreads();   // atomicOr(fsh) complete
  float thr = (fsh & 1) ? 1e-6f : ((fsh & 2) ? 1e-7f : 1e-8f);
  if (l15 == 0) {
#pragma unroll
    for (int k3 = 0; k3 < 2; ++k3) {
      int base = (wid * 2 + k3) * 16 + qq * 4;
#pragma unroll
      for (int j = 0; j < 4; ++j)
        sbuf[base + j] = (wq[k3][j] > thr) ? sp[k3][j] : -1e30f;
    }
  }
  __syncthreads();

  // ---------------- block softmax ----------------
  float sv = (t < CHB * 16) ? sbuf[t] : -1e30f;
  float m = sv;
#pragma unroll
  for (int d = 1; d < 64; d <<= 1) m = fmaxf(m, __shfl_xor(m, d));
  if (lane == 0) redw[wid] = m;
  __syncthreads();
  float mloc = fmaxf(fmaxf(redw[0], redw[1]), fmaxf(redw[2], redw[3]));
  float e = (t < CHB * 16) ? __expf(sv - mloc) : 0.f;
#pragma unroll
  for (int d = 1; d < 64; d <<= 1) e += __shfl_xor(e, d);
  if (lane == 0) redw[4 + wid] = e;
  __syncthreads();
  if (t == 0) { pm[b] = mloc; pl[b] = redw[4] + redw[5] + redw[6] + redw[7]; }

  // ---------------- phase B: PV (reuses a-frags/wq/uthF) ----------------
  float pvw[2][4];
#pragma unroll
  for (int k3 = 0; k3 < 2; ++k3)
#pragma unroll
    for (int j = 0; j < 4; ++j)
      pvw[k3][j] = __expf(sbuf[(wid * 2 + k3) * 16 + qq * 4 + j] - mloc);

  for (int half = 0; half < 2; ++half) {
    paccs[t] = 0.f;
    __syncthreads();
#pragma unroll 4
    for (int tt = 0; tt < 16; ++tt) {
      int c = half * 256 + tt * 16 + l15;
      short8 b0 = *(short8*)&uthF[qq * 512 + c];
      short8 b1 = (qq < 2) ? *(const short8*)&Utgp[(4 + qq) * 512 + c] : zero8;
      f32x4 btv = *(const f32x4*)&Btc[(size_t)c * 384 + dbase + qq * 4];
      const float* Ap = &A[(size_t)(h0 + wid * 2) * 512 + c];
      float av[2]; av[0] = Ap[0]; av[1] = Ap[512];
      float acc_t = 0.f;
#pragma unroll
      for (int k3 = 0; k3 < 2; ++k3) {
        f32x4 cc = (f32x4){0.f, 0.f, 0.f, 0.f};
        cc = __builtin_amdgcn_mfma_f32_16x16x32_bf16(a0[k3], b0, cc, 0, 0, 0);
        cc = __builtin_amdgcn_mfma_f32_16x16x32_bf16(a1[k3], b1, cc, 0, 0, 0);
        float aw = av[k3];
        float x0 = cc[0] + wq[k3][0] * (aw + btv[0]); float mb0 = fmaxf(x0, 0.01f * x0);
        float x1 = cc[1] + wq[k3][1] * (aw + btv[1]); float mb1 = fmaxf(x1, 0.01f * x1);
        float x2 = cc[2] + wq[k3][2] * (aw + btv[2]); float mb2 = fmaxf(x2, 0.01f * x2);
        float x3 = cc[3] + wq[k3][3] * (aw + btv[3]); float mb3 = fmaxf(x3, 0.01f * x3);
        acc_t = fmaf(pvw[k3][0], mb0, fmaf(pvw[k3][1], mb1,
                fmaf(pvw[k3][2], mb2, fmaf(pvw[k3][3], mb3, acc_t))));
      }
      acc_t += __shfl_xor(acc_t, 16);
      acc_t += __shfl_xor(acc_t, 32);
      if (lane < 16) atomicAdd(&paccs[tt * 16 + l15], acc_t);
    }
    __syncthreads();
    pacc[(size_t)b * 512 + half * 256 + t] = paccs[t];
    __syncthreads();
  }
}

// -------------------- combine + trailing GEMV fused (64 blocks x 16 cols) --------------------
__global__ __launch_bounds__(256) void k_gemvc(
    const float* __restrict__ W, const float* __restrict__ bias,
    const float* __restrict__ vbuf, const float* __restrict__ pm,
    const float* __restrict__ pl, const float* __restrict__ pacc,
    float* __restrict__ outA, float* __restrict__ out2) {
  __shared__ float xs[1024];
  __shared__ float sc[NBLK];
  __shared__ int slist[NBLK];
  __shared__ int scnt_sh;
  __shared__ float redm[8];
  __shared__ float red[256];
  int t = threadIdx.x;
  int lane = t & 63, wid = t >> 6;

  float m = -1e30f;
  for (int i = t; i < NBLK; i += 256) m = fmaxf(m, pm[i]);
#pragma unroll
  for (int d = 1; d < 64; d <<= 1) m = fmaxf(m, __shfl_xor(m, d));
  if (lane == 0) redm[wid] = m;
  __syncthreads();
  float M = fmaxf(fmaxf(redm[0], redm[1]), fmaxf(redm[2], redm[3]));
  float ls = 0.f;
  for (int i = t; i < NBLK; i += 256) {
    float d = pm[i] - M;
    float e = (d < -SKIP_LD) ? 0.f : __expf(d);
    sc[i] = e;
    ls += e * pl[i];
  }
#pragma unroll
  for (int d = 1; d < 64; d <<= 1) ls += __shfl_xor(ls, d);
  if (lane == 0) redm[4 + wid] = ls;
  __syncthreads();
  float L = redm[4] + redm[5] + redm[6] + redm[7];

  if (wid == 0) {   // deterministic survivor compaction
    int cnt = 0;
#pragma unroll
    for (int rnd = 0; rnd < NBLK / 64; ++rnd) {
      int bb = rnd * 64 + lane;
      bool p = sc[bb] > 0.f;
      unsigned long long mask = __ballot(p);
      int off = __popcll(mask & ((1ull << lane) - 1ull));
      if (p) slist[cnt + off] = bb;
      cnt += __popcll(mask);
    }
    if (lane == 0) scnt_sh = cnt;
  }
  __syncthreads();
  int S = scnt_sh;
  for (int c = t; c < 512; c += 256) xs[c] = vbuf[c];
#pragma unroll
  for (int half = 0; half < 2; ++half) {
    int c = t + half * 256;
    float s = 0.f;
    for (int k = 0; k < S; ++k) {
      int bb = slist[k];
      s += pacc[(size_t)bb * 512 + c] * sc[bb];
    }
    xs[512 + c] = s / L;
  }
  __syncthreads();

  int jj = t & 15, kq = t >> 4;           // 16 k-slices of 64
  int j = blockIdx.x * 16 + jj;
  float acc = 0.f;
#pragma unroll 8
  for (int k = kq * 64; k < kq * 64 + 64; ++k) acc = fmaf(xs[k], W[(size_t)k * 1024 + j], acc);
  red[kq * 16 + jj] = acc;
  __syncthreads();
  if (kq == 0) {
    float s = bias[j];
#pragma unroll
    for (int q = 0; q < 16; ++q) s += red[q * 16 + jj];
    float rv = lrelu(s);
    outA[j] = rv;
    if (out2) out2[j] = rv;
  }
}

// ------------------------------------------------------------------
extern "C" void kernel_launch(void* const* d_in, const int* in_sizes, int n_in,
                              void* d_out, int out_size, void* d_ws, size_t ws_size,
                              hipStream_t stream) {
  const float* E   = (const float*)d_in[0];
  const float* H   = (const float*)d_in[1];
  const float* e1  = (const float*)d_in[2];
  const float* e2  = (const float*)d_in[3];
  const float* rel = (const float*)d_in[5];
  const float* Wc  = (const float*)d_in[6];
  const float* bc  = (const float*)d_in[7];
  const float* Wk  = (const float*)d_in[8];
  const float* bk  = (const float*)d_in[9];
  const float* Wh  = (const float*)d_in[10];
  const float* bh  = (const float*)d_in[11];

  char* ws = (char*)d_ws;
  uint4*  ep     = (uint4*)(ws + EPACK_OFF);
  float*  marg   = (float*)(ws + MARG_OFF);
  float*  Abuf   = (float*)(ws + A_OFF);
  float*  Btc    = (float*)(ws + BTC_OFF);
  uint4*  Utgp   = (uint4*)(ws + UTGP_OFF);
  float*  xin    = (float*)(ws + XIN_OFF);
  float*  kbuf   = (float*)(ws + KBUF_OFF);
  float*  vbuf   = (float*)(ws + VBUF_OFF);
  float*  pm     = (float*)(ws + PM_OFF);
  float*  pl     = (float*)(ws + PL_OFF);
  float*  pacc   = (float*)(ws + PACC_OFF);
  int*    blkf   = (int*)(ws + BLKF_OFF);

  k_prep<<<481, 256, 0, stream>>>(E, ep, marg, blkf, H, Wc, rel, bc, Abuf, Btc, Utgp);

  for (int hop = 0; hop < 3; ++hop) {
    const float* Wki = Wk + (size_t)hop * 1024 * 1024;
    const float* bki = bk + (size_t)hop * 1024;
    const float* Whi = Wh + (size_t)hop * 1024 * 1024;
    const float* bhi = bh + (size_t)hop * 1024;
    k_gemv<<<64, 256, 0, stream>>>(Wki, bki, hop == 0 ? e1 : xin,
                                   hop == 0 ? e2 : xin + 512, kbuf, vbuf);
    k_fused<<<NBLK, 256, 0, stream>>>(ep, marg, Abuf, Btc, Utgp, blkf, kbuf,
                                      pm, pl, pacc);
    k_gemvc<<<64, 256, 0, stream>>>(Whi, bhi, vbuf, pm, pl, pacc, xin,
                                    hop == 2 ? (float*)d_out : (float*)nullptr);
  }
}

// Round 10
// 190.865 us; speedup vs baseline: 1.5853x; 1.4066x over previous
//
#include <hip/hip_runtime.h>
#include <hip/hip_bf16.h>
#include <cstdint>
#include <cstddef>

// Problem constants (R=45, L=384, D=512, E_REL=15, IN4=1024, HOPS=3)
#define LL      147456      // 384*384
#define NBLK    768         // 24 dbase-groups x 32 h-groups (3 blocks/CU exact)
#define CHB     12          // h values per block (3 per wave)
#define NPACK   288         // pack blocks (2 hd per thread)

typedef __attribute__((ext_vector_type(8))) short  short8;
typedef __attribute__((ext_vector_type(4))) float  f32x4;

// ---- workspace layout (bytes, 16B aligned) ----
#define EPACK_OFF   0u          // 6 planes * LL * 16B (bf16 E, plane-major, K=48)
#define MARG_OFF    14155776u   // LL*4
#define A_OFF       14745600u   // 384*512*4   A[h][c]
#define BTC_OFF     15532032u   // 512*384*4   Btc[c][d]  (c-major: f32x4 covers 16 d's)
#define UTGP_OFF    16318464u   // 6*512*16 (U plane-major [g][c] bf16x8)
#define XIN_OFF     16367616u   // 1024 f
#define KBUF_OFF    16371712u   // 512 f
#define VBUF_OFF    16373760u   // 512 f
#define PM_OFF      16377856u   // 768 f
#define PL_OFF      16380928u   // 768 f
#define PACC_OFF    16384000u   // 768*512*4 = 1,572,864
#define BLKF_OFF    17956864u   // NPACK ints

#define SKIP_LD     20.0f       // combine-side block skip: dropped mass ~3e-4 relative
#define PV_EPS      1e-8f       // PV wave-skip: dropped mass <= 144*1e-8 relative

static __device__ __forceinline__ ushort f2bf(float x) {
  uint u = __float_as_uint(x);
  return (ushort)((u + 0x7fffu + ((u >> 16) & 1u)) >> 16);   // RNE
}
static __device__ __forceinline__ float lrelu(float x) { return fmaxf(x, 0.01f * x); }

// ------------------------------------------------------------------
// Merged prep (unchanged known-good). GEMM blocks FIRST so pack backfills.
__global__ __launch_bounds__(256) void k_prep(
    const float* __restrict__ E, uint4* __restrict__ ep,
    float* __restrict__ marg, int* __restrict__ blkflags,
    const float* __restrict__ H, const float* __restrict__ Wc,
    const float* __restrict__ rel, const float* __restrict__ bc,
    float* __restrict__ A, float* __restrict__ Btc, uint4* __restrict__ Utgp) {
  __shared__ float Hs[4][512];
  __shared__ float Ps[4][512];
  __shared__ int fsh;
  int b = blockIdx.x, t = threadIdx.x;
  if (b < 192) {
    bool roleA = (b < 96);
    int g0 = (roleA ? b : b - 96) * 4;
    const float* Wcp = Wc + (size_t)(roleA ? 0 : 527) * 512;
    for (int i = t; i < 4 * 512; i += 256) Hs[i >> 9][i & 511] = H[(size_t)g0 * 512 + i];
    __syncthreads();
    int cq = t & 127, q = t >> 7;
    int c0 = cq * 4;
    f32x4 acc[4];
#pragma unroll
    for (int i = 0; i < 4; ++i) acc[i] = (f32x4){0.f, 0.f, 0.f, 0.f};
    for (int k = q * 256; k < q * 256 + 256; ++k) {
      f32x4 wv = *(const f32x4*)&Wcp[(size_t)k * 512 + c0];
#pragma unroll
      for (int i = 0; i < 4; ++i) { float hv = Hs[i][k]; acc[i] += hv * wv; }
    }
    if (q == 1) {
#pragma unroll
      for (int i = 0; i < 4; ++i) *(f32x4*)&Ps[i][c0] = acc[i];
    }
    __syncthreads();
    if (q == 0) {
#pragma unroll
      for (int i = 0; i < 4; ++i) {
        acc[i] += *(const f32x4*)&Ps[i][c0];
        if (roleA) {
          *(f32x4*)&A[(size_t)(g0 + i) * 512 + c0] = acc[i];
        } else {
#pragma unroll
          for (int j = 0; j < 4; ++j) Btc[(size_t)(c0 + j) * 384 + (g0 + i)] = acc[i][j];
        }
      }
    }
  } else if (b == 192) {
    for (int c = t; c < 512; c += 256) {
      float uv[48];
#pragma unroll
      for (int k = 0; k < 45; ++k) {
        float s = 0.f;
#pragma unroll
        for (int e = 0; e < 15; ++e) s += rel[k * 15 + e] * Wc[(size_t)(512 + e) * 512 + c];
        uv[k] = s;
      }
      uv[45] = bc[c]; uv[46] = 0.f; uv[47] = 0.f;
#pragma unroll
      for (int g = 0; g < 6; ++g) {
        uint w[4];
#pragma unroll
        for (int p = 0; p < 4; ++p)
          w[p] = (uint)f2bf(uv[g * 8 + 2 * p]) | ((uint)f2bf(uv[g * 8 + 2 * p + 1]) << 16);
        uint4 v; v.x = w[0]; v.y = w[1]; v.z = w[2]; v.w = w[3];
        Utgp[g * 512 + c] = v;
      }
    }
  } else {
    // pack role: 2 hd per thread, all 45 plane loads (float2) in flight
    if (t == 0) fsh = 0;
    int bp = b - 193;
    size_t hd0 = (size_t)bp * 512 + 2 * t;
    float2 ev[46];
#pragma unroll
    for (int r = 0; r < 45; ++r) ev[r] = *(const float2*)&E[(size_t)r * LL + hd0];
    ev[45] = make_float2(1.0f, 1.0f);   // slot45 = 1.0 for bc-fold
    float s0 = 0.f, s1 = 0.f;
#pragma unroll
    for (int r = 0; r < 45; ++r) { s0 += ev[r].x; s1 += ev[r].y; }
#pragma unroll
    for (int o = 0; o < 6; ++o) {
      uint wa[4], wb[4];
#pragma unroll
      for (int p = 0; p < 4; ++p) {
        int r0 = 8 * o + 2 * p, r1 = r0 + 1;
        float a0 = (r0 < 46) ? ev[r0].x : 0.f, a1 = (r1 < 46) ? ev[r1].x : 0.f;
        float b0 = (r0 < 46) ? ev[r0].y : 0.f, b1 = (r1 < 46) ? ev[r1].y : 0.f;
        wa[p] = (uint)f2bf(a0) | ((uint)f2bf(a1) << 16);
        wb[p] = (uint)f2bf(b0) | ((uint)f2bf(b1) << 16);
      }
      uint4 va; va.x = wa[0]; va.y = wa[1]; va.z = wa[2]; va.w = wa[3];
      uint4 vb; vb.x = wb[0]; vb.y = wb[1]; vb.z = wb[2]; vb.w = wb[3];
      ep[(size_t)o * LL + hd0] = va;
      ep[(size_t)o * LL + hd0 + 1] = vb;
    }
    *(float2*)&marg[hd0] = make_float2(s0, s1);
    int f = (s0 > 1e-6f ? 1 : 0) | (s0 > 1e-7f ? 2 : 0) | (s0 > 1e-8f ? 4 : 0)
          | (s1 > 1e-6f ? 1 : 0) | (s1 > 1e-7f ? 2 : 0) | (s1 > 1e-8f ? 4 : 0);
#pragma unroll
    for (int d = 1; d < 64; d <<= 1) f |= __shfl_xor(f, d);
    __syncthreads();
    if ((t & 63) == 0) atomicOr(&fsh, f);
    __syncthreads();
    if (t == 0) blkflags[bp] = fsh;
  }
}

// -------------------- leading GEMV (kv split), 64 blocks x 16 cols --------------------
__global__ __launch_bounds__(256) void k_gemv(const float* __restrict__ W, const float* __restrict__ bias,
                                              const float* __restrict__ xA, const float* __restrict__ xB,
                                              float* __restrict__ kbuf, float* __restrict__ vbuf) {
  __shared__ float xs[1024];
  __shared__ float red[256];
  int t = threadIdx.x;
  for (int i = t; i < 1024; i += 256) xs[i] = (i < 512) ? xA[i] : xB[i - 512];
  __syncthreads();
  int jj = t & 15, kq = t >> 4;           // 16 k-slices of 64
  int j = blockIdx.x * 16 + jj;
  float acc = 0.f;
#pragma unroll 8
  for (int k = kq * 64; k < kq * 64 + 64; ++k) acc = fmaf(xs[k], W[(size_t)k * 1024 + j], acc);
  red[kq * 16 + jj] = acc;
  __syncthreads();
  if (kq == 0) {
    float s = bias[j];
#pragma unroll
    for (int q = 0; q < 16; ++q) s += red[q * 16 + jj];
    if (j < 512) kbuf[j] = tanhf(s);
    else vbuf[j - 512] = lrelu(s);
  }
}

// -------------------- fused scores + block-softmax + PV (R7 structure) --------------------
// NEW vs R7: PV wave-skip. pvw = exp(s - mloc) is ultra-peaked; a wave whose 12
// rows all have pvw < PV_EPS contributes < 48e-8 relative mass -> skip its tt loop.
// Barriers stay outside the branch; >=1 wave per block is always active (pvw=1 row).
__global__ __launch_bounds__(256, 3) void k_fused(
    const uint4* __restrict__ ep, const float* __restrict__ marg,
    const float* __restrict__ A, const float* __restrict__ Btc,
    const uint4* __restrict__ Utgp, const int* __restrict__ blkflags,
    const float* __restrict__ kvec,
    float* __restrict__ pm, float* __restrict__ pl, float* __restrict__ pacc) {
  __shared__ __align__(16) uint4 uthF[6 * 512];   // 48KB: full U, staged once
  __shared__ float sbuf[CHB * 16];
  __shared__ float redw[8];
  __shared__ float paccs[256];
  __shared__ int fsh;
  int t = threadIdx.x, b = blockIdx.x;
  int dbt = b >> 5, hg = b & 31;
  int dbase = dbt * 16, h0 = hg * CHB;
  int lane = t & 63, wid = t >> 6;
  int l15 = lane & 15, qq = lane >> 4;

  if (t == 0) fsh = 0;
  for (int i = t; i < 6 * 512; i += 256) uthF[i] = Utgp[i];
  int f = 0;
  for (int i = t; i < NPACK; i += 256) f |= blkflags[i];
#pragma unroll
  for (int d = 1; d < 64; d <<= 1) f |= __shfl_xor(f, d);

  const short8 zero8 = (short8){0, 0, 0, 0, 0, 0, 0, 0};
  short8 a0[3], a1[3];
  f32x4 wq[3];
#pragma unroll
  for (int k3 = 0; k3 < 3; ++k3) {
    int h = h0 + wid * 3 + k3;
    int hda = h * 384 + dbase + l15;
    uint4 r0 = ep[(size_t)qq * LL + hda];
    a0[k3] = *(short8*)&r0;
    if (qq < 2) { uint4 r1 = ep[(size_t)(4 + qq) * LL + hda]; a1[k3] = *(short8*)&r1; }
    else a1[k3] = zero8;
    wq[k3] = *(const f32x4*)&marg[h * 384 + dbase + qq * 4];
  }
  __syncthreads();
  if ((t & 63) == 0) atomicOr(&fsh, f);

  // ---------------- phase A: scores ----------------
  float sp[3][4];
#pragma unroll
  for (int k3 = 0; k3 < 3; ++k3)
#pragma unroll
    for (int j = 0; j < 4; ++j) sp[k3][j] = 0.f;

  for (int half = 0; half < 2; ++half) {
    float kreg[16];
#pragma unroll
    for (int tt = 0; tt < 16; ++tt) kreg[tt] = kvec[half * 256 + tt * 16 + l15];
#pragma unroll 4
    for (int tt = 0; tt < 16; ++tt) {
      int c = half * 256 + tt * 16 + l15;
      short8 b0 = *(short8*)&uthF[qq * 512 + c];
      short8 b1 = (qq < 2) ? *(short8*)&uthF[(4 + qq) * 512 + c] : zero8;
      f32x4 btv = *(const f32x4*)&Btc[(size_t)c * 384 + dbase + qq * 4];
      const float* Ap = &A[(size_t)(h0 + wid * 3) * 512 + c];
      float av[3]; av[0] = Ap[0]; av[1] = Ap[512]; av[2] = Ap[1024];
#pragma unroll
      for (int k3 = 0; k3 < 3; ++k3) {
        f32x4 cc = (f32x4){0.f, 0.f, 0.f, 0.f};
        cc = __builtin_amdgcn_mfma_f32_16x16x32_bf16(a0[k3], b0, cc, 0, 0, 0);
        cc = __builtin_amdgcn_mfma_f32_16x16x32_bf16(a1[k3], b1, cc, 0, 0, 0);
        float aw = av[k3];
        float x0 = cc[0] + wq[k3][0] * (aw + btv[0]); float mb0 = fmaxf(x0, 0.01f * x0);
        float x1 = cc[1] + wq[k3][1] * (aw + btv[1]); float mb1 = fmaxf(x1, 0.01f * x1);
        float x2 = cc[2] + wq[k3][2] * (aw + btv[2]); float mb2 = fmaxf(x2, 0.01f * x2);
        float x3 = cc[3] + wq[k3][3] * (aw + btv[3]); float mb3 = fmaxf(x3, 0.01f * x3);
        sp[k3][0] = fmaf(mb0, kreg[tt], sp[k3][0]);
        sp[k3][1] = fmaf(mb1, kreg[tt], sp[k3][1]);
        sp[k3][2] = fmaf(mb2, kreg[tt], sp[k3][2]);
        sp[k3][3] = fmaf(mb3, kreg[tt], sp[k3][3]);
      }
    }
  }
#pragma unroll
  for (int k3 = 0; k3 < 3; ++k3)
#pragma unroll
    for (int j = 0; j < 4; ++j) {
#pragma unroll
      for (int d = 1; d < 16; d <<= 1) sp[k3][j] += __shfl_xor(sp[k3][j], d);
    }
  __syncthreads();   // atomicOr(fsh) complete
  float thr = (fsh & 1) ? 1e-6f : ((fsh & 2) ? 1e-7f : 1e-8f);
  if (l15 == 0) {
#pragma unroll
    for (int k3 = 0; k3 < 3; ++k3) {
      int base = (wid * 3 + k3) * 16 + qq * 4;
#pragma unroll
      for (int j = 0; j < 4; ++j)
        sbuf[base + j] = (wq[k3][j] > thr) ? sp[k3][j] : -1e30f;
    }
  }
  __syncthreads();

  // ---------------- block softmax ----------------
  float sv = (t < CHB * 16) ? sbuf[t] : -1e30f;
  float m = sv;
#pragma unroll
  for (int d = 1; d < 64; d <<= 1) m = fmaxf(m, __shfl_xor(m, d));
  if (lane == 0) redw[wid] = m;
  __syncthreads();
  float mloc = fmaxf(fmaxf(redw[0], redw[1]), fmaxf(redw[2], redw[3]));
  float e = (t < CHB * 16) ? __expf(sv - mloc) : 0.f;
#pragma unroll
  for (int d = 1; d < 64; d <<= 1) e += __shfl_xor(e, d);
  if (lane == 0) redw[4 + wid] = e;
  __syncthreads();
  if (t == 0) { pm[b] = mloc; pl[b] = redw[4] + redw[5] + redw[6] + redw[7]; }

  // ---------------- phase B: PV (wave-skip + reuse of a-frags/wq/uthF) ----------------
  float pvw[3][4];
  float lmax = 0.f;
#pragma unroll
  for (int k3 = 0; k3 < 3; ++k3)
#pragma unroll
    for (int j = 0; j < 4; ++j) {
      float p = __expf(sbuf[(wid * 3 + k3) * 16 + qq * 4 + j] - mloc);
      pvw[k3][j] = p;
      lmax = fmaxf(lmax, p);
    }
  bool active = !__all(lmax < PV_EPS);   // wave-uniform vote

  for (int half = 0; half < 2; ++half) {
    paccs[t] = 0.f;
    __syncthreads();
    if (active) {
#pragma unroll 4
      for (int tt = 0; tt < 16; ++tt) {
        int c = half * 256 + tt * 16 + l15;
        short8 b0 = *(short8*)&uthF[qq * 512 + c];
        short8 b1 = (qq < 2) ? *(short8*)&uthF[(4 + qq) * 512 + c] : zero8;
        f32x4 btv = *(const f32x4*)&Btc[(size_t)c * 384 + dbase + qq * 4];
        const float* Ap = &A[(size_t)(h0 + wid * 3) * 512 + c];
        float av[3]; av[0] = Ap[0]; av[1] = Ap[512]; av[2] = Ap[1024];
        float acc_t = 0.f;
#pragma unroll
        for (int k3 = 0; k3 < 3; ++k3) {
          f32x4 cc = (f32x4){0.f, 0.f, 0.f, 0.f};
          cc = __builtin_amdgcn_mfma_f32_16x16x32_bf16(a0[k3], b0, cc, 0, 0, 0);
          cc = __builtin_amdgcn_mfma_f32_16x16x32_bf16(a1[k3], b1, cc, 0, 0, 0);
          float aw = av[k3];
          float x0 = cc[0] + wq[k3][0] * (aw + btv[0]); float mb0 = fmaxf(x0, 0.01f * x0);
          float x1 = cc[1] + wq[k3][1] * (aw + btv[1]); float mb1 = fmaxf(x1, 0.01f * x1);
          float x2 = cc[2] + wq[k3][2] * (aw + btv[2]); float mb2 = fmaxf(x2, 0.01f * x2);
          float x3 = cc[3] + wq[k3][3] * (aw + btv[3]); float mb3 = fmaxf(x3, 0.01f * x3);
          acc_t = fmaf(pvw[k3][0], mb0, fmaf(pvw[k3][1], mb1,
                  fmaf(pvw[k3][2], mb2, fmaf(pvw[k3][3], mb3, acc_t))));
        }
        acc_t += __shfl_xor(acc_t, 16);
        acc_t += __shfl_xor(acc_t, 32);
        if (lane < 16) atomicAdd(&paccs[tt * 16 + l15], acc_t);
      }
    }
    __syncthreads();
    pacc[(size_t)b * 512 + half * 256 + t] = paccs[t];
    __syncthreads();
  }
}

// -------------------- combine + trailing GEMV fused (64 blocks x 16 cols) --------------------
__global__ __launch_bounds__(256) void k_gemvc(
    const float* __restrict__ W, const float* __restrict__ bias,
    const float* __restrict__ vbuf, const float* __restrict__ pm,
    const float* __restrict__ pl, const float* __restrict__ pacc,
    float* __restrict__ outA, float* __restrict__ out2) {
  __shared__ float xs[1024];
  __shared__ float sc[NBLK];
  __shared__ int slist[NBLK];
  __shared__ int scnt_sh;
  __shared__ float redm[8];
  __shared__ float red[256];
  int t = threadIdx.x;
  int lane = t & 63, wid = t >> 6;

  float m = -1e30f;
  for (int i = t; i < NBLK; i += 256) m = fmaxf(m, pm[i]);
#pragma unroll
  for (int d = 1; d < 64; d <<= 1) m = fmaxf(m, __shfl_xor(m, d));
  if (lane == 0) redm[wid] = m;
  __syncthreads();
  float M = fmaxf(fmaxf(redm[0], redm[1]), fmaxf(redm[2], redm[3]));
  float ls = 0.f;
  for (int i = t; i < NBLK; i += 256) {
    float d = pm[i] - M;
    float e = (d < -SKIP_LD) ? 0.f : __expf(d);
    sc[i] = e;
    ls += e * pl[i];
  }
#pragma unroll
  for (int d = 1; d < 64; d <<= 1) ls += __shfl_xor(ls, d);
  if (lane == 0) redm[4 + wid] = ls;
  __syncthreads();
  float L = redm[4] + redm[5] + redm[6] + redm[7];

  if (wid == 0) {   // deterministic survivor compaction
    int cnt = 0;
#pragma unroll
    for (int rnd = 0; rnd < NBLK / 64; ++rnd) {
      int bb = rnd * 64 + lane;
      bool p = sc[bb] > 0.f;
      unsigned long long mask = __ballot(p);
      int off = __popcll(mask & ((1ull << lane) - 1ull));
      if (p) slist[cnt + off] = bb;
      cnt += __popcll(mask);
    }
    if (lane == 0) scnt_sh = cnt;
  }
  __syncthreads();
  int S = scnt_sh;
  for (int c = t; c < 512; c += 256) xs[c] = vbuf[c];
#pragma unroll
  for (int half = 0; half < 2; ++half) {
    int c = t + half * 256;
    float s = 0.f;
    for (int k = 0; k < S; ++k) {
      int bb = slist[k];
      s += pacc[(size_t)bb * 512 + c] * sc[bb];
    }
    xs[512 + c] = s / L;
  }
  __syncthreads();

  int jj = t & 15, kq = t >> 4;           // 16 k-slices of 64
  int j = blockIdx.x * 16 + jj;
  float acc = 0.f;
#pragma unroll 8
  for (int k = kq * 64; k < kq * 64 + 64; ++k) acc = fmaf(xs[k], W[(size_t)k * 1024 + j], acc);
  red[kq * 16 + jj] = acc;
  __syncthreads();
  if (kq == 0) {
    float s = bias[j];
#pragma unroll
    for (int q = 0; q < 16; ++q) s += red[q * 16 + jj];
    float rv = lrelu(s);
    outA[j] = rv;
    if (out2) out2[j] = rv;
  }
}

// ------------------------------------------------------------------
extern "C" void kernel_launch(void* const* d_in, const int* in_sizes, int n_in,
                              void* d_out, int out_size, void* d_ws, size_t ws_size,
                              hipStream_t stream) {
  const float* E   = (const float*)d_in[0];
  const float* H   = (const float*)d_in[1];
  const float* e1  = (const float*)d_in[2];
  const float* e2  = (const float*)d_in[3];
  const float* rel = (const float*)d_in[5];
  const float* Wc  = (const float*)d_in[6];
  const float* bc  = (const float*)d_in[7];
  const float* Wk  = (const float*)d_in[8];
  const float* bk  = (const float*)d_in[9];
  const float* Wh  = (const float*)d_in[10];
  const float* bh  = (const float*)d_in[11];

  char* ws = (char*)d_ws;
  uint4*  ep     = (uint4*)(ws + EPACK_OFF);
  float*  marg   = (float*)(ws + MARG_OFF);
  float*  Abuf   = (float*)(ws + A_OFF);
  float*  Btc    = (float*)(ws + BTC_OFF);
  uint4*  Utgp   = (uint4*)(ws + UTGP_OFF);
  float*  xin    = (float*)(ws + XIN_OFF);
  float*  kbuf   = (float*)(ws + KBUF_OFF);
  float*  vbuf   = (float*)(ws + VBUF_OFF);
  float*  pm     = (float*)(ws + PM_OFF);
  float*  pl     = (float*)(ws + PL_OFF);
  float*  pacc   = (float*)(ws + PACC_OFF);
  int*    blkf   = (int*)(ws + BLKF_OFF);

  k_prep<<<481, 256, 0, stream>>>(E, ep, marg, blkf, H, Wc, rel, bc, Abuf, Btc, Utgp);

  for (int hop = 0; hop < 3; ++hop) {
    const float* Wki = Wk + (size_t)hop * 1024 * 1024;
    const float* bki = bk + (size_t)hop * 1024;
    const float* Whi = Wh + (size_t)hop * 1024 * 1024;
    const float* bhi = bh + (size_t)hop * 1024;
    k_gemv<<<64, 256, 0, stream>>>(Wki, bki, hop == 0 ? e1 : xin,
                                   hop == 0 ? e2 : xin + 512, kbuf, vbuf);
    k_fused<<<NBLK, 256, 0, stream>>>(ep, marg, Abuf, Btc, Utgp, blkf, kbuf,
                                      pm, pl, pacc);
    k_gemvc<<<64, 256, 0, stream>>>(Whi, bhi, vbuf, pm, pl, pacc, xin,
                                    hop == 2 ? (float*)d_out : (float*)nullptr);
  }
}